// Round 6
// baseline (77.196 us; speedup 1.0000x reference)
//
#include <hip/hip_runtime.h>

// AutoCorrelation attention — wave-decoupled FFT (4096 = 4 x 1024).
// B=16, L=4096, D=64, k=24.
// R6: stage-0 radix-4 is register-local; each wave runs a private 1024-pt
// FFT (16x16x4) in its own 8KB LDS region with wave-level sync only.
// Block barriers: 9 (was ~14); the big FFT stretches are wave-independent.

#define FFT_N 4096
#define TOPK  24
#define PI2   6.28318530717958647692f
#define C16_1 0.92387953251128675613f   // cos(pi/8)
#define S16_1 0.38268343236508977173f   // sin(pi/8)
#define C16_2 0.70710678118654752440f   // cos(pi/4)

__device__ __forceinline__ float2 cmul(float2 a, float2 b) {
  return make_float2(a.x*b.x - a.y*b.y, a.x*b.y + a.y*b.x);
}

__device__ __forceinline__ void wave_sync() {
  // intra-wave LDS producer->consumer fence: all our ds_writes committed,
  // and no compiler reordering across this point. No cross-wave semantics.
  asm volatile("s_waitcnt lgkmcnt(0)" ::: "memory");
  __builtin_amdgcn_wave_barrier();
}

// 16-point DFT, natural order in and out. S=-1 forward, S=+1 inverse.
template<int S>
__device__ __forceinline__ void fft16(float2* x) {
  const float sg = (float)S;
  float2 y[16];
#pragma unroll
  for (int n2 = 0; n2 < 4; ++n2) {
    float2 a = x[n2], b = x[4+n2], c = x[8+n2], d = x[12+n2];
    float t0r=a.x+c.x, t0i=a.y+c.y, t1r=a.x-c.x, t1i=a.y-c.y;
    float t2r=b.x+d.x, t2i=b.y+d.y, t3r=b.x-d.x, t3i=b.y-d.y;
    y[n2*4+0] = make_float2(t0r+t2r, t0i+t2i);
    y[n2*4+2] = make_float2(t0r-t2r, t0i-t2i);
    y[n2*4+1] = make_float2(t1r - sg*t3i, t1i + sg*t3r);
    y[n2*4+3] = make_float2(t1r + sg*t3i, t1i - sg*t3r);
  }
#define CTW(ii, cc, ss) { float2 v=y[ii]; y[ii]=make_float2(v.x*(cc)-v.y*(sg*(ss)), v.x*(sg*(ss))+v.y*(cc)); }
  CTW(5,  C16_1, S16_1)
  CTW(6,  C16_2, C16_2)
  CTW(7,  S16_1, C16_1)
  CTW(9,  C16_2, C16_2)
  { float2 v = y[10]; y[10] = make_float2(-sg*v.y, sg*v.x); }
  CTW(11, -C16_2, C16_2)
  CTW(13, S16_1, C16_1)
  CTW(14, -C16_2, C16_2)
  CTW(15, -C16_1, -S16_1)
#undef CTW
#pragma unroll
  for (int k1 = 0; k1 < 4; ++k1) {
    float2 a = y[k1], b = y[4+k1], c = y[8+k1], d = y[12+k1];
    float t0r=a.x+c.x, t0i=a.y+c.y, t1r=a.x-c.x, t1i=a.y-c.y;
    float t2r=b.x+d.x, t2i=b.y+d.y, t3r=b.x-d.x, t3i=b.y-d.y;
    x[k1+0]  = make_float2(t0r+t2r, t0i+t2i);
    x[k1+8]  = make_float2(t0r-t2r, t0i-t2i);
    x[k1+4]  = make_float2(t1r - sg*t3i, t1i + sg*t3r);
    x[k1+12] = make_float2(t1r + sg*t3i, t1i - sg*t3r);
  }
}

// radix-4 butterfly, natural in/out. S=-1 fwd, +1 inv. out[k]=sum in[n] w4^{S n k}
template<int S>
__device__ __forceinline__ void radix4(const float2* in, float2* out) {
  const float sg = (float)S;
  float t0r=in[0].x+in[2].x, t0i=in[0].y+in[2].y;
  float t1r=in[0].x-in[2].x, t1i=in[0].y-in[2].y;
  float t2r=in[1].x+in[3].x, t2i=in[1].y+in[3].y;
  float t3r=in[1].x-in[3].x, t3i=in[1].y-in[3].y;
  out[0] = make_float2(t0r+t2r, t0i+t2i);
  out[1] = make_float2(t1r - sg*t3i, t1i + sg*t3r);
  out[2] = make_float2(t0r-t2r, t0i-t2i);
  out[3] = make_float2(t1r + sg*t3i, t1i - sg*t3r);
}

// x[k] *= w^k, k=1..15; powers via depth-4 product tree.
__device__ __forceinline__ void twiddle_chain(float2* x, float ang) {
  float sb, cb; __sincosf(ang, &sb, &cb);
  float2 w1 = make_float2(cb, sb);
  float2 w2 = cmul(w1,w1), w3 = cmul(w1,w2);
  float2 w4 = cmul(w2,w2), w5 = cmul(w2,w3), w6 = cmul(w3,w3), w7 = cmul(w3,w4);
  float2 w8 = cmul(w4,w4), w9 = cmul(w4,w5), w10 = cmul(w5,w5), w11 = cmul(w5,w6);
  float2 w12 = cmul(w6,w6), w13 = cmul(w6,w7), w14 = cmul(w7,w7), w15 = cmul(w7,w8);
  x[1]=cmul(x[1],w1);   x[2]=cmul(x[2],w2);   x[3]=cmul(x[3],w3);
  x[4]=cmul(x[4],w4);   x[5]=cmul(x[5],w5);   x[6]=cmul(x[6],w6);
  x[7]=cmul(x[7],w7);   x[8]=cmul(x[8],w8);   x[9]=cmul(x[9],w9);
  x[10]=cmul(x[10],w10); x[11]=cmul(x[11],w11); x[12]=cmul(x[12],w12);
  x[13]=cmul(x[13],w13); x[14]=cmul(x[14],w14); x[15]=cmul(x[15],w15);
}

// wave-private LDS layout helpers (addresses within a 1024-float2 region)
__device__ __forceinline__ int loc2(int q1, int n2, int n3) {
  return (q1<<6) + ((n2 ^ q1)<<2) + n3;
}
__device__ __forceinline__ int loc3(int q1, int q2, int n3) {
  return (q1<<6) + ((q2 ^ q1)<<2) + (n3 ^ (q2 & 3));
}
__device__ __forceinline__ int locU(int q) {
  return q ^ ((q >> 4) & 15);
}

// 1024-pt FFT within one wave. Input: x[n1] = z[64*n1 + l] (registers).
// Output: x[gg*4 + q3] = X[q1g + 16*q2g + 256*q3], q1g=(l+64gg)>>4, q2g=l&15.
// W = 1024-float2 wave-private LDS region. Two internal wave syncs.
template<int S>
__device__ __forceinline__ void wave_fft1024(float2* x, float2* W, int l) {
  const float sgn = (float)S;
  fft16<S>(x);
  twiddle_chain(x, sgn * PI2 * (float)l * (1.0f/1024.f));
  const int n2w = l >> 2, n3w = l & 3;
#pragma unroll
  for (int q1 = 0; q1 < 16; ++q1) W[loc2(q1, n2w, n3w)] = x[q1];
  wave_sync();
  const int q1r = l >> 2, n3r = l & 3;
#pragma unroll
  for (int m = 0; m < 16; ++m) x[m] = W[loc2(q1r, m, n3r)];
  fft16<S>(x);
  twiddle_chain(x, sgn * PI2 * (float)n3r * (1.0f/64.f));
#pragma unroll
  for (int q2 = 0; q2 < 16; ++q2) W[loc3(q1r, q2, n3r)] = x[q2];
  wave_sync();
  float2 xx[16];
#pragma unroll
  for (int gg = 0; gg < 4; ++gg) {
    int gid = l + (gg << 6);
    int q1g = gid >> 4, q2g = gid & 15;
#pragma unroll
    for (int n3i = 0; n3i < 4; ++n3i)
      xx[(gg<<2)+n3i] = W[loc3(q1g, q2g, n3i)];
  }
#pragma unroll
  for (int gg = 0; gg < 4; ++gg)
    radix4<S>(&xx[gg<<2], &x[gg<<2]);
}

// Q,K [B,L,D] -> interleaved float2 (q,k) in [B,D,L]
__global__ __launch_bounds__(256) void transposeQK(const float* __restrict__ Q,
                                                   const float* __restrict__ K,
                                                   float2* __restrict__ ZQK) {
  __shared__ float tq[64][65];
  __shared__ float tk[64][65];
  const int b = blockIdx.y;
  const int t0 = blockIdx.x << 6;
  const float* Qb = Q + ((size_t)b << 18);
  const float* Kb = K + ((size_t)b << 18);
  int tx = threadIdx.x & 63, ty = threadIdx.x >> 6;
#pragma unroll
  for (int i = 0; i < 16; ++i) {
    int r = (i << 2) + ty;
    tq[r][tx] = Qb[(size_t)(t0 + r) * 64 + tx];
    tk[r][tx] = Kb[(size_t)(t0 + r) * 64 + tx];
  }
  __syncthreads();
  float2* outb = ZQK + ((size_t)b << 18);
#pragma unroll
  for (int i = 0; i < 16; ++i) {
    int d = (i << 2) + ty;
    outb[(size_t)d * 4096 + t0 + tx] = make_float2(tq[tx][d], tk[tx][d]);
  }
}

__global__ __launch_bounds__(256) void transpose64(const float* __restrict__ in,
                                                   float* __restrict__ out,
                                                   int R, int C) {
  __shared__ float tile[64][65];
  int tiles_c = C >> 6;
  int tr = blockIdx.x / tiles_c;
  int tc = blockIdx.x - tr * tiles_c;
  const float* inb = in + (size_t)blockIdx.y * R * C;
  float* outb = out + (size_t)blockIdx.y * R * C;
  int tx = threadIdx.x & 63;
  int ty = threadIdx.x >> 6;
  int r0 = tr << 6, c0 = tc << 6;
#pragma unroll
  for (int i = 0; i < 16; ++i) {
    int r = (i << 2) + ty;
    tile[r][tx] = inb[(size_t)(r0 + r) * C + (c0 + tx)];
  }
  __syncthreads();
#pragma unroll
  for (int i = 0; i < 16; ++i) {
    int r = (i << 2) + ty;
    outb[(size_t)(c0 + r) * R + (r0 + tx)] = tile[tx][r];
  }
}

__global__ __launch_bounds__(256, 4) void corr_kernel(const float2* __restrict__ ZQK,
                                                      const float* __restrict__ Vt,
                                                      float* __restrict__ At) {
  __shared__ float2 Z[FFT_N];          // 32 KiB, the only shared array

  const int tid = threadIdx.x;
  const int w = tid >> 6, l = tid & 63;
  float2* W = Z + (w << 10);           // wave-private 1024-float2 region
  const size_t row = (size_t)blockIdx.x << 12;

  float2 x[16];

  // ---- load z = q + i*k : thread holds n = 256*j + tid, j=0..15 ----
#pragma unroll
  for (int j = 0; j < 16; ++j)
    x[j] = ZQK[row + (j << 8) + tid];

  // ---- stage 0: register-local radix-4 over stride 1024 (DIF) ----
  {
#pragma unroll
    for (int j = 0; j < 4; ++j) {
      int n0 = (j << 8) + tid;
      float2 in4[4] = { x[j], x[j+4], x[j+8], x[j+12] };
      float2 u[4];
      radix4<-1>(in4, u);
      float ang = -PI2 * (float)n0 * (1.0f/4096.f);
      float s1, c1; __sincosf(ang, &s1, &c1);
      float2 w1 = make_float2(c1, s1);
      float2 w2 = cmul(w1, w1), w3 = cmul(w1, w2);
      Z[n0]        = u[0];
      Z[1024 + n0] = cmul(u[1], w1);
      Z[2048 + n0] = cmul(u[2], w2);
      Z[3072 + n0] = cmul(u[3], w3);
    }
  }
  __syncthreads();   // (1) distribution to wave regions

  // ---- forward wave-private 1024-pt FFT on branch r = w ----
#pragma unroll
  for (int n1 = 0; n1 < 16; ++n1) x[n1] = W[(n1 << 6) + l];
  wave_fft1024<-1>(x, W, l);
  // write U_w[q] (swizzled natural) for pointwise
#pragma unroll
  for (int gg = 0; gg < 4; ++gg) {
    int gid = l + (gg << 6);
    int q1g = gid >> 4, q2g = gid & 15;
    int qb = q1g + (q2g << 4);
#pragma unroll
    for (int q3 = 0; q3 < 4; ++q3)
      W[locU(qb + (q3 << 8))] = x[(gg<<2) + q3];
  }
  __syncthreads();   // (2) all U regions visible

  // ---- pointwise P[4q+w] = Qf*conj(Kf)*(1/4N); feeds inverse lvl1 regs ----
  {
    const int rp = (4 - w) & 3;
    const float2* Wp = Z + (rp << 10);
    const float scale = 0.25f / 4096.f;
#pragma unroll
    for (int n1 = 0; n1 < 16; ++n1) {
      int q  = (n1 << 6) + l;
      int qp = (w == 0) ? ((1024 - q) & 1023) : (1023 - q);
      float2 A  = W[locU(q)];
      float2 Bv = Wp[locU(qp)];
      float ur = A.x + Bv.x, ui = A.y - Bv.y;
      float vr = A.x - Bv.x, vi = -A.y - Bv.y;
      float xr = ur*vr - ui*vi, xi = ur*vi + ui*vr;
      x[n1] = make_float2(-xi * scale, xr * scale);
    }
  }
  __syncthreads();   // (3) all pointwise reads done before regions rewritten

  // prefetch V row (latency hidden under inverse FFT)
  float4 v4s[4];
#pragma unroll
  for (int mm = 0; mm < 4; ++mm)
    v4s[mm] = *(const float4*)&Vt[row + (tid << 2) + (mm << 10)];

  // ---- inverse wave-private 1024-pt FFT (unnormalized) ----
  wave_fft1024<1>(x, W, l);

  // ---- phi-twiddle v' = v * e^{+2pi i w n0/4096}, write to region ----
  {
    float s16, c16; __sincosf(PI2 * (float)w * (1.0f/16.f), &s16, &c16);
    float2 f1 = make_float2(c16, s16), f2 = cmul(f1, f1), f3 = cmul(f1, f2);
#pragma unroll
    for (int gg = 0; gg < 4; ++gg) {
      int g2 = (l >> 4) + (gg << 2) + ((l & 15) << 4);   // q1g + 16*q2g
      float ang = PI2 * (float)(w * g2) * (1.0f/4096.f);
      float sg_, cg_; __sincosf(ang, &sg_, &cg_);
      float2 pg = make_float2(cg_, sg_);
      float2 p1 = cmul(pg, f1), p2 = cmul(pg, f2), p3 = cmul(pg, f3);
      W[locU(g2)]        = cmul(x[(gg<<2)+0], pg);
      W[locU(g2 + 256)]  = cmul(x[(gg<<2)+1], p1);
      W[locU(g2 + 512)]  = cmul(x[(gg<<2)+2], p2);
      W[locU(g2 + 768)]  = cmul(x[(gg<<2)+3], p3);
    }
  }
  __syncthreads();   // (4) all v' regions visible

  // ---- recombination: Rxx[n0 + 1024m] = Re( sum_r v'_r[n0] i^{rm} ) ----
  float rr[16];      // rr[jj + 4m] at global index tid + 256*(jj+4m)
#pragma unroll
  for (int jj = 0; jj < 4; ++jj) {
    int n0 = tid + (jj << 8);
    int lv = locU(n0);
    float2 v0 = Z[lv], v1 = Z[1024 + lv], v2 = Z[2048 + lv], v3 = Z[3072 + lv];
    float s02 = v0.x + v2.x, d02 = v0.x - v2.x;
    float s13 = v1.x + v3.x, d13 = v1.y - v3.y;
    rr[jj]      = s02 + s13;
    rr[jj + 4]  = d02 - d13;
    rr[jj + 8]  = s02 - s13;
    rr[jj + 12] = d02 + d13;
  }
  __syncthreads();   // (5) recomb reads done; Z free

  // ---- stage V0 copy + local top-5 candidates ----
  float* Vf = (float*)Z;
#pragma unroll
  for (int mm = 0; mm < 4; ++mm) {
    int n0 = (tid << 2) + (mm << 10);
    *(float4*)&Vf[n0] = v4s[mm];                   // V0: floats [0..4095]
  }
  {
    float c0v=-3e38f,c1v=-3e38f,c2v=-3e38f,c3v=-3e38f,c4v=-3e38f;
    int   c0i=0x7fffffff,c1i=0x7fffffff,c2i=0x7fffffff,c3i=0x7fffffff,c4i=0x7fffffff;
#pragma unroll
    for (int d = 0; d < 16; ++d) {                 // ascending global index
      float v = rr[d];
      int  gi = tid + (d << 8);
      bool g0 = v > c0v, g1 = v > c1v, g2 = v > c2v, g3 = v > c3v, g4 = v > c4v;
      c4v = g3 ? c3v : (g4 ? v : c4v);  c4i = g3 ? c3i : (g4 ? gi : c4i);
      c3v = g2 ? c2v : (g3 ? v : c3v);  c3i = g2 ? c2i : (g3 ? gi : c3i);
      c2v = g1 ? c1v : (g2 ? v : c2v);  c2i = g1 ? c1i : (g2 ? gi : c2i);
      c1v = g0 ? c0v : (g1 ? v : c1v);  c1i = g0 ? c0i : (g1 ? gi : c1i);
      c0v = g0 ? v : c0v;               c0i = g0 ? gi : c0i;
    }
    const int cb = 2048 + tid * 5;                 // inside future-V1 region
    Z[cb+0] = make_float2(c0v, __int_as_float(c0i));
    Z[cb+1] = make_float2(c1v, __int_as_float(c1i));
    Z[cb+2] = make_float2(c2v, __int_as_float(c2i));
    Z[cb+3] = make_float2(c3v, __int_as_float(c3i));
    Z[cb+4] = make_float2(c4v, __int_as_float(c4i));
  }
  __syncthreads();   // B1: candidates + V0 visible

  // ---- wave-0 only: top-24 via 4-run sorted merge ----
  if (tid < 64) {
    const int cb0 = 2048 + (tid      ) * 5;
    const int cb1 = 2048 + (tid +  64) * 5;
    const int cb2 = 2048 + (tid + 128) * 5;
    const int cb3 = 2048 + (tid + 192) * 5;
    int p0 = 0, p1 = 0, p2 = 0, p3 = 0;
    float m0s = 0.f, esum = 0.f;
#pragma unroll 1
    for (int t = 0; t < TOPK; ++t) {
      float2 h0 = Z[cb0 + (p0 < 5 ? p0 : 4)];
      float2 h1 = Z[cb1 + (p1 < 5 ? p1 : 4)];
      float2 h2 = Z[cb2 + (p2 < 5 ? p2 : 4)];
      float2 h3 = Z[cb3 + (p3 < 5 ? p3 : 4)];
      float hv0 = (p0 < 5) ? h0.x : -3e38f;  int hi0 = __float_as_int(h0.y);
      float hv1 = (p1 < 5) ? h1.x : -3e38f;  int hi1 = __float_as_int(h1.y);
      float hv2 = (p2 < 5) ? h2.x : -3e38f;  int hi2 = __float_as_int(h2.y);
      float hv3 = (p3 < 5) ? h3.x : -3e38f;  int hi3 = __float_as_int(h3.y);
      float bv = hv0; int bi = hi0;
      if (hv1 > bv || (hv1 == bv && hi1 < bi)) { bv = hv1; bi = hi1; }
      if (hv2 > bv || (hv2 == bv && hi2 < bi)) { bv = hv2; bi = hi2; }
      if (hv3 > bv || (hv3 == bv && hi3 < bi)) { bv = hv3; bi = hi3; }
#pragma unroll
      for (int off = 32; off; off >>= 1) {
        float ov = __shfl_xor(bv, off);
        int   oi = __shfl_xor(bi, off);
        if (ov > bv || (ov == bv && oi < bi)) { bv = ov; bi = oi; }
      }
      p0 += (hi0 == bi) ? 1 : 0;
      p1 += (hi1 == bi) ? 1 : 0;
      p2 += (hi2 == bi) ? 1 : 0;
      p3 += (hi3 == bi) ? 1 : 0;
      if (t == 0) m0s = bv;
      float e = __expf(bv - m0s);
      esum += e;
      if (tid == 0) Z[3400 + t] = make_float2(e, __int_as_float(bi));
    }
    if (tid == 0) Z[3400 + TOPK] = make_float2(esum, 0.f);
  }
  __syncthreads();   // B2: pack written

  // ---- broadcast pack into registers (before V1 overwrites it) ----
  float wk[TOPK]; int ikr[TOPK];
#pragma unroll
  for (int t = 0; t < TOPK; ++t) {
    float2 p = Z[3400 + t];
    wk[t] = p.x;  ikr[t] = __float_as_int(p.y);
  }
  const float inv = 1.0f / Z[3400 + TOPK].x;
  __syncthreads();   // B2': pack reads complete

  // ---- stage V1 shifted copy ----
#pragma unroll
  for (int mm = 0; mm < 4; ++mm) {
    int n0 = (tid << 2) + (mm << 10);
    float4 v = v4s[mm];
    Vf[4096 + ((n0 - 1) & 4095)] = v.x;
    Vf[4096 + n0]     = v.y;
    Vf[4096 + n0 + 1] = v.z;
    Vf[4096 + n0 + 2] = v.w;
  }
  __syncthreads();   // B3

  // ---- gather: A[l] = inv * sum_t e_t * V[(l + i_t) % N] ----
#pragma unroll
  for (int mm = 0; mm < 8; ++mm) {
    int ll = (tid << 1) + (mm << 9);
    float accx = 0.f, accy = 0.f;
#pragma unroll
    for (int t = 0; t < TOPK; ++t) {
      int ik = ikr[t];
      int e  = (ll + (ik & ~1)) & 4095;
      float2 vv = *(float2*)&Vf[((ik & 1) << 12) + e];
      accx += wk[t] * vv.x;
      accy += wk[t] * vv.y;
    }
    *(float2*)&At[row + ll] = make_float2(accx * inv, accy * inv);
  }
}

extern "C" void kernel_launch(void* const* d_in, const int* in_sizes, int n_in,
                              void* d_out, int out_size, void* d_ws, size_t ws_size,
                              hipStream_t stream) {
  const float* Q = (const float*)d_in[0];
  const float* K = (const float*)d_in[1];
  const float* V = (const float*)d_in[2];
  float* out = (float*)d_out;
  float* wsf = (float*)d_ws;

  const int B = 16;
  const size_t SLAB = (size_t)4194304;       // B*L*D floats
  float2* ZQK = (float2*)wsf;                // 2*SLAB floats
  float*  Vt  = wsf + 2 * SLAB;
  float*  At  = Vt;   // alias: block i reads Vt row i (to regs) before writing

  dim3 blk(256);
  transposeQK<<<dim3(64, B), blk, 0, stream>>>(Q, K, ZQK);
  transpose64<<<dim3(64, B), blk, 0, stream>>>(V, Vt, 4096, 64);

  corr_kernel<<<dim3(B * 64), blk, 0, stream>>>(ZQK, Vt, At);

  transpose64<<<dim3(64, B), blk, 0, stream>>>(At, out, 64, 4096);
}

// Round 7
// 76.724 us; speedup vs baseline: 1.0061x; 1.0061x over previous
//
#include <hip/hip_runtime.h>

// AutoCorrelation attention — wave-decoupled FFT (4096 = 4 x 1024), spill-fixed.
// B=16, L=4096, D=64, k=24.
// R7: R6's structure with (a) WSYNC without "memory" clobber (sched_barrier
// sandwich), (b) zero escaping arrays (macro-inlined wave FFT, scalar radix-4),
// (c) twiddle recurrences, (d) fused QKV transpose kernel.

#define FFT_N 4096
#define TOPK  24
#define PI2   6.28318530717958647692f
#define C16_1 0.92387953251128675613f   // cos(pi/8)
#define S16_1 0.38268343236508977173f   // sin(pi/8)
#define C16_2 0.70710678118654752440f   // cos(pi/4)

__device__ __forceinline__ float2 cmul(float2 a, float2 b) {
  return make_float2(a.x*b.x - a.y*b.y, a.x*b.y + a.y*b.x);
}

// Intra-wave LDS producer->consumer fence. No memory clobber (keeps SROA'd
// registers out of scratch); sched_barrier(0) pins all code motion, the
// volatile waitcnt drains the DS queue. (guide §5 rule 18 pattern)
#define WSYNC() do {                          \
  __builtin_amdgcn_sched_barrier(0);          \
  asm volatile("s_waitcnt lgkmcnt(0)");       \
  __builtin_amdgcn_sched_barrier(0);          \
} while (0)

// 16-point DFT, natural order in and out. S=-1 forward, S=+1 inverse.
template<int S>
__device__ __forceinline__ void fft16(float2* x) {
  const float sg = (float)S;
  float2 y[16];
#pragma unroll
  for (int n2 = 0; n2 < 4; ++n2) {
    float2 a = x[n2], b = x[4+n2], c = x[8+n2], d = x[12+n2];
    float t0r=a.x+c.x, t0i=a.y+c.y, t1r=a.x-c.x, t1i=a.y-c.y;
    float t2r=b.x+d.x, t2i=b.y+d.y, t3r=b.x-d.x, t3i=b.y-d.y;
    y[n2*4+0] = make_float2(t0r+t2r, t0i+t2i);
    y[n2*4+2] = make_float2(t0r-t2r, t0i-t2i);
    y[n2*4+1] = make_float2(t1r - sg*t3i, t1i + sg*t3r);
    y[n2*4+3] = make_float2(t1r + sg*t3i, t1i - sg*t3r);
  }
#define CTW(ii, cc, ss) { float2 v=y[ii]; y[ii]=make_float2(v.x*(cc)-v.y*(sg*(ss)), v.x*(sg*(ss))+v.y*(cc)); }
  CTW(5,  C16_1, S16_1)
  CTW(6,  C16_2, C16_2)
  CTW(7,  S16_1, C16_1)
  CTW(9,  C16_2, C16_2)
  { float2 v = y[10]; y[10] = make_float2(-sg*v.y, sg*v.x); }
  CTW(11, -C16_2, C16_2)
  CTW(13, S16_1, C16_1)
  CTW(14, -C16_2, C16_2)
  CTW(15, -C16_1, -S16_1)
#undef CTW
#pragma unroll
  for (int k1 = 0; k1 < 4; ++k1) {
    float2 a = y[k1], b = y[4+k1], c = y[8+k1], d = y[12+k1];
    float t0r=a.x+c.x, t0i=a.y+c.y, t1r=a.x-c.x, t1i=a.y-c.y;
    float t2r=b.x+d.x, t2i=b.y+d.y, t3r=b.x-d.x, t3i=b.y-d.y;
    x[k1+0]  = make_float2(t0r+t2r, t0i+t2i);
    x[k1+8]  = make_float2(t0r-t2r, t0i-t2i);
    x[k1+4]  = make_float2(t1r - sg*t3i, t1i + sg*t3r);
    x[k1+12] = make_float2(t1r + sg*t3i, t1i - sg*t3r);
  }
}

// x[k] *= w^k, k=1..15; powers via depth-4 product tree.
__device__ __forceinline__ void twiddle_chain(float2* x, float ang) {
  float sb, cb; __sincosf(ang, &sb, &cb);
  float2 w1 = make_float2(cb, sb);
  float2 w2 = cmul(w1,w1), w3 = cmul(w1,w2);
  float2 w4 = cmul(w2,w2), w5 = cmul(w2,w3), w6 = cmul(w3,w3), w7 = cmul(w3,w4);
  float2 w8 = cmul(w4,w4), w9 = cmul(w4,w5), w10 = cmul(w5,w5), w11 = cmul(w5,w6);
  float2 w12 = cmul(w6,w6), w13 = cmul(w6,w7), w14 = cmul(w7,w7), w15 = cmul(w7,w8);
  x[1]=cmul(x[1],w1);   x[2]=cmul(x[2],w2);   x[3]=cmul(x[3],w3);
  x[4]=cmul(x[4],w4);   x[5]=cmul(x[5],w5);   x[6]=cmul(x[6],w6);
  x[7]=cmul(x[7],w7);   x[8]=cmul(x[8],w8);   x[9]=cmul(x[9],w9);
  x[10]=cmul(x[10],w10); x[11]=cmul(x[11],w11); x[12]=cmul(x[12],w12);
  x[13]=cmul(x[13],w13); x[14]=cmul(x[14],w14); x[15]=cmul(x[15],w15);
}

// wave-private LDS layout helpers (indices within a 1024-float2 region)
__device__ __forceinline__ int loc2(int q1, int n2, int n3) {
  return (q1<<6) + ((n2 ^ q1)<<2) + n3;
}
__device__ __forceinline__ int loc3(int q1, int q2, int n3) {
  return (q1<<6) + ((q2 ^ q1)<<2) + (n3 ^ (q2 & 3));
}
__device__ __forceinline__ int locU(int q) {
  return q ^ ((q >> 4) & 15);
}

// 1024-pt FFT within one wave, fully inline (no escaping arrays).
// In: x[n1] = u[64*n1 + l]. Out: x[gg*4+q3] = X[q1g + 16*q2g + 256*q3],
// q1g=(l+64gg)>>4, q2g=l&15. Two WSYNCs, no block barriers.
#define WAVE_FFT1024(S) do {                                                  \
  fft16<(S)>(x);                                                              \
  twiddle_chain(x, (float)(S) * PI2 * (float)l * (1.0f/1024.f));              \
  { const int n2w = l >> 2, n3w = l & 3;                                      \
    _Pragma("unroll")                                                         \
    for (int q1 = 0; q1 < 16; ++q1) W[loc2(q1, n2w, n3w)] = x[q1]; }          \
  WSYNC();                                                                    \
  { const int q1r = l >> 2, n3r = l & 3;                                      \
    _Pragma("unroll")                                                         \
    for (int m = 0; m < 16; ++m) x[m] = W[loc2(q1r, m, n3r)];                 \
    fft16<(S)>(x);                                                            \
    twiddle_chain(x, (float)(S) * PI2 * (float)n3r * (1.0f/64.f));            \
    _Pragma("unroll")                                                         \
    for (int q2 = 0; q2 < 16; ++q2) W[loc3(q1r, q2, n3r)] = x[q2]; }          \
  WSYNC();                                                                    \
  { const float sgf = (float)(S);                                             \
    _Pragma("unroll")                                                         \
    for (int gg = 0; gg < 4; ++gg) {                                          \
      int gid = l + (gg << 6);                                                \
      int q1g = gid >> 4, q2g = gid & 15;                                     \
      float2 Ar = W[loc3(q1g, q2g, 0)];                                       \
      float2 Br = W[loc3(q1g, q2g, 1)];                                       \
      float2 Cr = W[loc3(q1g, q2g, 2)];                                       \
      float2 Dr = W[loc3(q1g, q2g, 3)];                                       \
      float t0r=Ar.x+Cr.x, t0i=Ar.y+Cr.y, t1r=Ar.x-Cr.x, t1i=Ar.y-Cr.y;       \
      float t2r=Br.x+Dr.x, t2i=Br.y+Dr.y, t3r=Br.x-Dr.x, t3i=Br.y-Dr.y;       \
      x[(gg<<2)+0] = make_float2(t0r+t2r, t0i+t2i);                           \
      x[(gg<<2)+1] = make_float2(t1r - sgf*t3i, t1i + sgf*t3r);               \
      x[(gg<<2)+2] = make_float2(t0r-t2r, t0i-t2i);                           \
      x[(gg<<2)+3] = make_float2(t1r + sgf*t3i, t1i - sgf*t3r);               \
    } }                                                                       \
} while (0)

// Q,K,V [B,L,D] -> ZQK interleaved float2 [B,D,L] + Vt [B,D,L]
__global__ __launch_bounds__(256) void transposeQKV(const float* __restrict__ Q,
                                                    const float* __restrict__ K,
                                                    const float* __restrict__ V,
                                                    float2* __restrict__ ZQK,
                                                    float* __restrict__ Vt) {
  __shared__ float tq[64][65];
  __shared__ float tk[64][65];
  __shared__ float tv[64][65];
  const int b = blockIdx.y;
  const int t0 = blockIdx.x << 6;
  const float* Qb = Q + ((size_t)b << 18);
  const float* Kb = K + ((size_t)b << 18);
  const float* Vb = V + ((size_t)b << 18);
  int tx = threadIdx.x & 63, ty = threadIdx.x >> 6;
#pragma unroll
  for (int i = 0; i < 16; ++i) {
    int r = (i << 2) + ty;
    tq[r][tx] = Qb[(size_t)(t0 + r) * 64 + tx];
    tk[r][tx] = Kb[(size_t)(t0 + r) * 64 + tx];
    tv[r][tx] = Vb[(size_t)(t0 + r) * 64 + tx];
  }
  __syncthreads();
  float2* zoutb = ZQK + ((size_t)b << 18);
  float*  voutb = Vt + ((size_t)b << 18);
#pragma unroll
  for (int i = 0; i < 16; ++i) {
    int d = (i << 2) + ty;
    zoutb[(size_t)d * 4096 + t0 + tx] = make_float2(tq[tx][d], tk[tx][d]);
    voutb[(size_t)d * 4096 + t0 + tx] = tv[tx][d];
  }
}

__global__ __launch_bounds__(256) void transpose64(const float* __restrict__ in,
                                                   float* __restrict__ out,
                                                   int R, int C) {
  __shared__ float tile[64][65];
  int tiles_c = C >> 6;
  int tr = blockIdx.x / tiles_c;
  int tc = blockIdx.x - tr * tiles_c;
  const float* inb = in + (size_t)blockIdx.y * R * C;
  float* outb = out + (size_t)blockIdx.y * R * C;
  int tx = threadIdx.x & 63;
  int ty = threadIdx.x >> 6;
  int r0 = tr << 6, c0 = tc << 6;
#pragma unroll
  for (int i = 0; i < 16; ++i) {
    int r = (i << 2) + ty;
    tile[r][tx] = inb[(size_t)(r0 + r) * C + (c0 + tx)];
  }
  __syncthreads();
#pragma unroll
  for (int i = 0; i < 16; ++i) {
    int r = (i << 2) + ty;
    outb[(size_t)(c0 + r) * R + (r0 + tx)] = tile[tx][r];
  }
}

__global__ __launch_bounds__(256, 4) void corr_kernel(const float2* __restrict__ ZQK,
                                                      const float* __restrict__ Vt,
                                                      float* __restrict__ At) {
  __shared__ float2 Z[FFT_N];          // 32 KiB, the only shared array

  const int tid = threadIdx.x;
  const int w = tid >> 6, l = tid & 63;
  float2* W = Z + (w << 10);           // wave-private 1024-float2 region
  const size_t row = (size_t)blockIdx.x << 12;

  float2 x[16];

  // ---- load z = q + i*k : x[j] = z[256*j + tid] ----
#pragma unroll
  for (int j = 0; j < 16; ++j)
    x[j] = ZQK[row + (j << 8) + tid];

  // ---- stage 0: register-local radix-4 over stride 1024 (DIF), scalar form.
  //      twiddle recurrence: w(n0+256) = w(n0) * e^{-i*pi/8} ----
  {
    float sb, cb; __sincosf(-PI2 * (float)tid * (1.0f/4096.f), &sb, &cb);
    float2 w1 = make_float2(cb, sb);
    const float2 stp = make_float2(C16_1, -S16_1);
#pragma unroll
    for (int j = 0; j < 4; ++j) {
      int n0 = (j << 8) + tid;
      float2 Ar = x[j], Br = x[j+4], Cr = x[j+8], Dr = x[j+12];
      float t0r=Ar.x+Cr.x, t0i=Ar.y+Cr.y, t1r=Ar.x-Cr.x, t1i=Ar.y-Cr.y;
      float t2r=Br.x+Dr.x, t2i=Br.y+Dr.y, t3r=Br.x-Dr.x, t3i=Br.y-Dr.y;
      float2 u1 = make_float2(t1r + t3i, t1i - t3r);   // t1 - i t3
      float2 u2 = make_float2(t0r - t2r, t0i - t2i);
      float2 u3 = make_float2(t1r - t3i, t1i + t3r);   // t1 + i t3
      float2 w2 = cmul(w1, w1), w3 = cmul(w1, w2);
      Z[n0]        = make_float2(t0r + t2r, t0i + t2i);
      Z[1024 + n0] = cmul(u1, w1);
      Z[2048 + n0] = cmul(u2, w2);
      Z[3072 + n0] = cmul(u3, w3);
      w1 = cmul(w1, stp);
    }
  }
  __syncthreads();   // (1) distribution to wave regions

  // ---- forward wave-private 1024-pt FFT on branch r = w ----
#pragma unroll
  for (int n1 = 0; n1 < 16; ++n1) x[n1] = W[(n1 << 6) + l];
  WAVE_FFT1024(-1);
  // spectrum write (swizzled natural)
#pragma unroll
  for (int gg = 0; gg < 4; ++gg) {
    int gid = l + (gg << 6);
    int qb = (gid >> 4) + ((gid & 15) << 4);
#pragma unroll
    for (int q3 = 0; q3 < 4; ++q3)
      W[locU(qb + (q3 << 8))] = x[(gg<<2) + q3];
  }
  __syncthreads();   // (2) all U regions visible

  // ---- pointwise P[4q+w] = Qf*conj(Kf)*(1/4N) -> inverse lvl1 registers ----
  {
    const int rp = (4 - w) & 3;
    const float2* Wp = Z + (rp << 10);
    const float scale = 0.25f / 4096.f;
#pragma unroll
    for (int n1 = 0; n1 < 16; ++n1) {
      int q  = (n1 << 6) + l;
      int qp = (w == 0) ? ((1024 - q) & 1023) : (1023 - q);
      float2 A  = W[locU(q)];
      float2 Bv = Wp[locU(qp)];
      float ur = A.x + Bv.x, ui = A.y - Bv.y;
      float vr = A.x - Bv.x, vi = -A.y - Bv.y;
      float xr = ur*vr - ui*vi, xi = ur*vi + ui*vr;
      x[n1] = make_float2(-xi * scale, xr * scale);
    }
  }
  __syncthreads();   // (3) pointwise reads done before regions rewritten

  // prefetch V row (latency hidden under inverse FFT; vmcnt untouched by WSYNC)
  float4 v4s[4];
#pragma unroll
  for (int mm = 0; mm < 4; ++mm)
    v4s[mm] = *(const float4*)&Vt[row + (tid << 2) + (mm << 10)];

  // ---- inverse wave-private 1024-pt FFT (unnormalized) ----
  WAVE_FFT1024(1);

  // ---- phi-twiddle v' = v * e^{+2pi i w n0/4096} (recurrence over gg) ----
  {
    float s16, c16; __sincosf(PI2 * (float)w * (1.0f/16.f), &s16, &c16);
    float2 f1 = make_float2(c16, s16), f2 = cmul(f1, f1), f3 = cmul(f1, f2);
    int g2 = (l >> 4) + ((l & 15) << 4);
    float sg0, cg0; __sincosf(PI2 * (float)(w * g2) * (1.0f/4096.f), &sg0, &cg0);
    float2 pg = make_float2(cg0, sg0);
    float sgs, cgs; __sincosf(PI2 * (float)w * (1.0f/1024.f), &sgs, &cgs);
    float2 pstep = make_float2(cgs, sgs);
#pragma unroll
    for (int gg = 0; gg < 4; ++gg) {
      int g2g = g2 + (gg << 2);
      W[locU(g2g)]       = cmul(x[(gg<<2)+0], pg);
      W[locU(g2g + 256)] = cmul(x[(gg<<2)+1], cmul(pg, f1));
      W[locU(g2g + 512)] = cmul(x[(gg<<2)+2], cmul(pg, f2));
      W[locU(g2g + 768)] = cmul(x[(gg<<2)+3], cmul(pg, f3));
      pg = cmul(pg, pstep);
    }
  }
  __syncthreads();   // (4) all v' regions visible

  // ---- recombination: Rxx[n0 + 1024m] = Re( sum_r v'_r[n0] i^{rm} ) ----
  float rr[16];      // rr[jj + 4m] at global index tid + 256*(jj+4m)
#pragma unroll
  for (int jj = 0; jj < 4; ++jj) {
    int n0 = tid + (jj << 8);
    int lv = locU(n0);
    float2 v0 = Z[lv], v1 = Z[1024 + lv], v2 = Z[2048 + lv], v3 = Z[3072 + lv];
    float s02 = v0.x + v2.x, d02 = v0.x - v2.x;
    float s13 = v1.x + v3.x, d13 = v1.y - v3.y;
    rr[jj]      = s02 + s13;
    rr[jj + 4]  = d02 - d13;
    rr[jj + 8]  = s02 - s13;
    rr[jj + 12] = d02 + d13;
  }
  __syncthreads();   // (5) recomb reads done; Z free

  // ---- stage V0 copy + local top-5 candidates ----
  float* Vf = (float*)Z;
#pragma unroll
  for (int mm = 0; mm < 4; ++mm) {
    int n0 = (tid << 2) + (mm << 10);
    *(float4*)&Vf[n0] = v4s[mm];                   // V0: floats [0..4095]
  }
  {
    float c0v=-3e38f,c1v=-3e38f,c2v=-3e38f,c3v=-3e38f,c4v=-3e38f;
    int   c0i=0x7fffffff,c1i=0x7fffffff,c2i=0x7fffffff,c3i=0x7fffffff,c4i=0x7fffffff;
#pragma unroll
    for (int d = 0; d < 16; ++d) {                 // ascending global index
      float v = rr[d];
      int  gi = tid + (d << 8);
      bool g0 = v > c0v, g1 = v > c1v, g2 = v > c2v, g3 = v > c3v, g4 = v > c4v;
      c4v = g3 ? c3v : (g4 ? v : c4v);  c4i = g3 ? c3i : (g4 ? gi : c4i);
      c3v = g2 ? c2v : (g3 ? v : c3v);  c3i = g2 ? c2i : (g3 ? gi : c3i);
      c2v = g1 ? c1v : (g2 ? v : c2v);  c2i = g1 ? c1i : (g2 ? gi : c2i);
      c1v = g0 ? c0v : (g1 ? v : c1v);  c1i = g0 ? c0i : (g1 ? gi : c1i);
      c0v = g0 ? v : c0v;               c0i = g0 ? gi : c0i;
    }
    const int cb = 2048 + tid * 5;                 // inside future-V1 region
    Z[cb+0] = make_float2(c0v, __int_as_float(c0i));
    Z[cb+1] = make_float2(c1v, __int_as_float(c1i));
    Z[cb+2] = make_float2(c2v, __int_as_float(c2i));
    Z[cb+3] = make_float2(c3v, __int_as_float(c3i));
    Z[cb+4] = make_float2(c4v, __int_as_float(c4i));
  }
  __syncthreads();   // B1: candidates + V0 visible

  // ---- wave-0 only: top-24 via 4-run sorted merge ----
  if (tid < 64) {
    const int cb0 = 2048 + (tid      ) * 5;
    const int cb1 = 2048 + (tid +  64) * 5;
    const int cb2 = 2048 + (tid + 128) * 5;
    const int cb3 = 2048 + (tid + 192) * 5;
    int p0 = 0, p1 = 0, p2 = 0, p3 = 0;
    float m0s = 0.f, esum = 0.f;
#pragma unroll 1
    for (int t = 0; t < TOPK; ++t) {
      float2 h0 = Z[cb0 + (p0 < 5 ? p0 : 4)];
      float2 h1 = Z[cb1 + (p1 < 5 ? p1 : 4)];
      float2 h2 = Z[cb2 + (p2 < 5 ? p2 : 4)];
      float2 h3 = Z[cb3 + (p3 < 5 ? p3 : 4)];
      float hv0 = (p0 < 5) ? h0.x : -3e38f;  int hi0 = __float_as_int(h0.y);
      float hv1 = (p1 < 5) ? h1.x : -3e38f;  int hi1 = __float_as_int(h1.y);
      float hv2 = (p2 < 5) ? h2.x : -3e38f;  int hi2 = __float_as_int(h2.y);
      float hv3 = (p3 < 5) ? h3.x : -3e38f;  int hi3 = __float_as_int(h3.y);
      float bv = hv0; int bi = hi0;
      if (hv1 > bv || (hv1 == bv && hi1 < bi)) { bv = hv1; bi = hi1; }
      if (hv2 > bv || (hv2 == bv && hi2 < bi)) { bv = hv2; bi = hi2; }
      if (hv3 > bv || (hv3 == bv && hi3 < bi)) { bv = hv3; bi = hi3; }
#pragma unroll
      for (int off = 32; off; off >>= 1) {
        float ov = __shfl_xor(bv, off);
        int   oi = __shfl_xor(bi, off);
        if (ov > bv || (ov == bv && oi < bi)) { bv = ov; bi = oi; }
      }
      p0 += (hi0 == bi) ? 1 : 0;
      p1 += (hi1 == bi) ? 1 : 0;
      p2 += (hi2 == bi) ? 1 : 0;
      p3 += (hi3 == bi) ? 1 : 0;
      if (t == 0) m0s = bv;
      float e = __expf(bv - m0s);
      esum += e;
      if (tid == 0) Z[3400 + t] = make_float2(e, __int_as_float(bi));
    }
    if (tid == 0) Z[3400 + TOPK] = make_float2(esum, 0.f);
  }
  __syncthreads();   // B2: pack written

  // ---- broadcast pack into registers (before V1 overwrites it) ----
  float wk[TOPK]; int ikr[TOPK];
#pragma unroll
  for (int t = 0; t < TOPK; ++t) {
    float2 p = Z[3400 + t];
    wk[t] = p.x;  ikr[t] = __float_as_int(p.y);
  }
  const float inv = 1.0f / Z[3400 + TOPK].x;
  __syncthreads();   // B2': pack reads complete

  // ---- stage V1 shifted copy ----
#pragma unroll
  for (int mm = 0; mm < 4; ++mm) {
    int n0 = (tid << 2) + (mm << 10);
    float4 v = v4s[mm];
    Vf[4096 + ((n0 - 1) & 4095)] = v.x;
    Vf[4096 + n0]     = v.y;
    Vf[4096 + n0 + 1] = v.z;
    Vf[4096 + n0 + 2] = v.w;
  }
  __syncthreads();   // B3

  // ---- gather: A[l] = inv * sum_t e_t * V[(l + i_t) % N] ----
#pragma unroll
  for (int mm = 0; mm < 8; ++mm) {
    int ll = (tid << 1) + (mm << 9);
    float accx = 0.f, accy = 0.f;
#pragma unroll
    for (int t = 0; t < TOPK; ++t) {
      int ik = ikr[t];
      int e  = (ll + (ik & ~1)) & 4095;
      float2 vv = *(float2*)&Vf[((ik & 1) << 12) + e];
      accx += wk[t] * vv.x;
      accy += wk[t] * vv.y;
    }
    *(float2*)&At[row + ll] = make_float2(accx * inv, accy * inv);
  }
}

extern "C" void kernel_launch(void* const* d_in, const int* in_sizes, int n_in,
                              void* d_out, int out_size, void* d_ws, size_t ws_size,
                              hipStream_t stream) {
  const float* Q = (const float*)d_in[0];
  const float* K = (const float*)d_in[1];
  const float* V = (const float*)d_in[2];
  float* out = (float*)d_out;
  float* wsf = (float*)d_ws;

  const int B = 16;
  const size_t SLAB = (size_t)4194304;       // B*L*D floats
  float2* ZQK = (float2*)wsf;                // 2*SLAB floats
  float*  Vt  = wsf + 2 * SLAB;
  float*  At  = Vt;   // alias: block i reads Vt row i (to regs) before writing

  dim3 blk(256);
  transposeQKV<<<dim3(64, B), blk, 0, stream>>>(Q, K, V, ZQK, Vt);
  corr_kernel<<<dim3(B * 64), blk, 0, stream>>>(ZQK, Vt, At);
  transpose64<<<dim3(64, B), blk, 0, stream>>>(At, out, 64, 4096);
}

// Round 8
// 73.838 us; speedup vs baseline: 1.0455x; 1.0391x over previous
//
#include <hip/hip_runtime.h>

// AutoCorrelation attention — register-resident 3-level radix-16 FFT (R5 core)
// + fully parallel top-k tail (per-wave shuffle merge + rank-merge), no
// register arrays in the tail (scratch-free), fused QKV transpose.
// B=16, L=4096, D=64, k=24.

#define FFT_N 4096
#define TOPK  24
#define PI2   6.28318530717958647692f
#define C16_1 0.92387953251128675613f   // cos(pi/8)
#define S16_1 0.38268343236508977173f   // sin(pi/8)
#define C16_2 0.70710678118654752440f   // cos(pi/4)

__device__ __forceinline__ float2 cmul(float2 a, float2 b) {
  return make_float2(a.x*b.x - a.y*b.y, a.x*b.y + a.y*b.x);
}

// 16-point DFT, natural order in and out. S=-1 forward, S=+1 inverse.
template<int S>
__device__ __forceinline__ void fft16(float2* x) {
  const float sg = (float)S;
  float2 y[16];
#pragma unroll
  for (int n2 = 0; n2 < 4; ++n2) {
    float2 a = x[n2], b = x[4+n2], c = x[8+n2], d = x[12+n2];
    float t0r=a.x+c.x, t0i=a.y+c.y, t1r=a.x-c.x, t1i=a.y-c.y;
    float t2r=b.x+d.x, t2i=b.y+d.y, t3r=b.x-d.x, t3i=b.y-d.y;
    y[n2*4+0] = make_float2(t0r+t2r, t0i+t2i);
    y[n2*4+2] = make_float2(t0r-t2r, t0i-t2i);
    y[n2*4+1] = make_float2(t1r - sg*t3i, t1i + sg*t3r);
    y[n2*4+3] = make_float2(t1r + sg*t3i, t1i - sg*t3r);
  }
#define CTW(ii, cc, ss) { float2 v=y[ii]; y[ii]=make_float2(v.x*(cc)-v.y*(sg*(ss)), v.x*(sg*(ss))+v.y*(cc)); }
  CTW(5,  C16_1, S16_1)
  CTW(6,  C16_2, C16_2)
  CTW(7,  S16_1, C16_1)
  CTW(9,  C16_2, C16_2)
  { float2 v = y[10]; y[10] = make_float2(-sg*v.y, sg*v.x); }
  CTW(11, -C16_2, C16_2)
  CTW(13, S16_1, C16_1)
  CTW(14, -C16_2, C16_2)
  CTW(15, -C16_1, -S16_1)
#undef CTW
#pragma unroll
  for (int k1 = 0; k1 < 4; ++k1) {
    float2 a = y[k1], b = y[4+k1], c = y[8+k1], d = y[12+k1];
    float t0r=a.x+c.x, t0i=a.y+c.y, t1r=a.x-c.x, t1i=a.y-c.y;
    float t2r=b.x+d.x, t2i=b.y+d.y, t3r=b.x-d.x, t3i=b.y-d.y;
    x[k1+0]  = make_float2(t0r+t2r, t0i+t2i);
    x[k1+8]  = make_float2(t0r-t2r, t0i-t2i);
    x[k1+4]  = make_float2(t1r - sg*t3i, t1i + sg*t3r);
    x[k1+12] = make_float2(t1r + sg*t3i, t1i - sg*t3r);
  }
}

// x[k] *= w^k, k=1..15; powers via depth-4 product tree.
__device__ __forceinline__ void twiddle_chain(float2* x, float ang) {
  float sb, cb; __sincosf(ang, &sb, &cb);
  float2 w1 = make_float2(cb, sb);
  float2 w2 = cmul(w1,w1), w3 = cmul(w1,w2);
  float2 w4 = cmul(w2,w2), w5 = cmul(w2,w3), w6 = cmul(w3,w3), w7 = cmul(w3,w4);
  float2 w8 = cmul(w4,w4), w9 = cmul(w4,w5), w10 = cmul(w5,w5), w11 = cmul(w5,w6);
  float2 w12 = cmul(w6,w6), w13 = cmul(w6,w7), w14 = cmul(w7,w7), w15 = cmul(w7,w8);
  x[1]=cmul(x[1],w1);   x[2]=cmul(x[2],w2);   x[3]=cmul(x[3],w3);
  x[4]=cmul(x[4],w4);   x[5]=cmul(x[5],w5);   x[6]=cmul(x[6],w6);
  x[7]=cmul(x[7],w7);   x[8]=cmul(x[8],w8);   x[9]=cmul(x[9],w9);
  x[10]=cmul(x[10],w10); x[11]=cmul(x[11],w11); x[12]=cmul(x[12],w12);
  x[13]=cmul(x[13],w13); x[14]=cmul(x[14],w14); x[15]=cmul(x[15],w15);
}

// Q,K,V [B,L,D] -> ZQK interleaved float2 [B,D,L] + Vt [B,D,L]
__global__ __launch_bounds__(256) void transposeQKV(const float* __restrict__ Q,
                                                    const float* __restrict__ K,
                                                    const float* __restrict__ V,
                                                    float2* __restrict__ ZQK,
                                                    float* __restrict__ Vt) {
  __shared__ float tq[64][65];
  __shared__ float tk[64][65];
  __shared__ float tv[64][65];
  const int b = blockIdx.y;
  const int t0 = blockIdx.x << 6;
  const float* Qb = Q + ((size_t)b << 18);
  const float* Kb = K + ((size_t)b << 18);
  const float* Vb = V + ((size_t)b << 18);
  int tx = threadIdx.x & 63, ty = threadIdx.x >> 6;
#pragma unroll
  for (int i = 0; i < 16; ++i) {
    int r = (i << 2) + ty;
    tq[r][tx] = Qb[(size_t)(t0 + r) * 64 + tx];
    tk[r][tx] = Kb[(size_t)(t0 + r) * 64 + tx];
    tv[r][tx] = Vb[(size_t)(t0 + r) * 64 + tx];
  }
  __syncthreads();
  float2* zoutb = ZQK + ((size_t)b << 18);
  float*  voutb = Vt + ((size_t)b << 18);
#pragma unroll
  for (int i = 0; i < 16; ++i) {
    int d = (i << 2) + ty;
    zoutb[(size_t)d * 4096 + t0 + tx] = make_float2(tq[tx][d], tk[tx][d]);
    voutb[(size_t)d * 4096 + t0 + tx] = tv[tx][d];
  }
}

__global__ __launch_bounds__(256) void transpose64(const float* __restrict__ in,
                                                   float* __restrict__ out,
                                                   int R, int C) {
  __shared__ float tile[64][65];
  int tiles_c = C >> 6;
  int tr = blockIdx.x / tiles_c;
  int tc = blockIdx.x - tr * tiles_c;
  const float* inb = in + (size_t)blockIdx.y * R * C;
  float* outb = out + (size_t)blockIdx.y * R * C;
  int tx = threadIdx.x & 63;
  int ty = threadIdx.x >> 6;
  int r0 = tr << 6, c0 = tc << 6;
#pragma unroll
  for (int i = 0; i < 16; ++i) {
    int r = (i << 2) + ty;
    tile[r][tx] = inb[(size_t)(r0 + r) * C + (c0 + tx)];
  }
  __syncthreads();
#pragma unroll
  for (int i = 0; i < 16; ++i) {
    int r = (i << 2) + ty;
    outb[(size_t)(c0 + r) * R + (r0 + tx)] = tile[tx][r];
  }
}

__global__ __launch_bounds__(256, 4) void corr_kernel(const float2* __restrict__ ZQK,
                                                      const float* __restrict__ Vt,
                                                      float* __restrict__ At) {
  __shared__ float2 Z[FFT_N];          // 32 KiB: FFT workspace, then V0+V1
  __shared__ float2 lists[4][TOPK];    // per-wave sorted top-24
  __shared__ float2 pack[TOPK + 1];    // final (e, idx) + esum

  const int tid = threadIdx.x;
  const int w = tid >> 6, l = tid & 63;
  const size_t row = (size_t)blockIdx.x << 12;

  float2 x[16];

  // ======== forward FFT of z = q + i*k (R5 core, verbatim) ========
#pragma unroll
  for (int n1 = 0; n1 < 16; ++n1)
    x[n1] = ZQK[row + (n1 << 8) + tid];
  fft16<-1>(x);
  twiddle_chain(x, -PI2 * (float)tid / 4096.f);
#pragma unroll
  for (int k = 0; k < 16; ++k) Z[(k << 8) + tid] = x[k];
  __syncthreads();
  {
    const int k1 = tid >> 4, b = tid & 15;
#pragma unroll
    for (int a = 0; a < 16; ++a) x[a] = Z[(k1 << 8) + (a << 4) + b];
    fft16<-1>(x);
    twiddle_chain(x, -PI2 * (float)b / 256.f);
    __syncthreads();
#pragma unroll
    for (int cc = 0; cc < 16; ++cc) Z[(k1 << 8) + (cc << 4) + (b ^ cc)] = x[cc];
  }
  __syncthreads();
  {
    const int k1 = tid >> 4, c = tid & 15;
#pragma unroll
    for (int bb = 0; bb < 16; ++bb) x[bb] = Z[(k1 << 8) + (c << 4) + (bb ^ c)];
    fft16<-1>(x);
    __syncthreads();
    const int bf = k1 + (c << 4);
#pragma unroll
    for (int d = 0; d < 16; ++d) Z[(bf ^ c) + (d << 8)] = x[d];
  }
  __syncthreads();

  // ======== pointwise P = Qf*conj(Kf) * (1/4N) ========
  {
    const float scale = 0.25f / 4096.f;
    const int x1 = tid >> 4;
#pragma unroll
    for (int f1 = 0; f1 < 16; ++f1) {
      int f  = (f1 << 8) + tid;
      int fp = (4096 - f) & 4095;
      float2 A  = Z[f ^ x1];
      float2 Bv = Z[fp ^ ((fp >> 4) & 15)];
      float ur = A.x + Bv.x, ui = A.y - Bv.y;
      float vr = A.x - Bv.x, vi = -A.y - Bv.y;
      float xr = ur*vr - ui*vi, xi = ur*vi + ui*vr;
      x[f1] = make_float2(-xi * scale, xr * scale);
    }
  }

  // prefetch V row (latency hidden under inverse FFT)
  float4 v4s[4];
#pragma unroll
  for (int mm = 0; mm < 4; ++mm)
    v4s[mm] = *(const float4*)&Vt[row + (tid << 2) + (mm << 10)];

  // ======== inverse FFT (R5 core, verbatim) ========
  fft16<1>(x);
  twiddle_chain(x, PI2 * (float)tid / 4096.f);
  __syncthreads();
#pragma unroll
  for (int k = 0; k < 16; ++k) Z[(k << 8) + tid] = x[k];
  __syncthreads();
  {
    const int k1 = tid >> 4, b = tid & 15;
#pragma unroll
    for (int a = 0; a < 16; ++a) x[a] = Z[(k1 << 8) + (a << 4) + b];
    fft16<1>(x);
    twiddle_chain(x, PI2 * (float)b / 256.f);
    __syncthreads();
#pragma unroll
    for (int cc = 0; cc < 16; ++cc) Z[(k1 << 8) + (cc << 4) + (b ^ cc)] = x[cc];
  }
  __syncthreads();
  float rr[16];
  {
    const int k1 = tid >> 4, c = tid & 15;
#pragma unroll
    for (int bb = 0; bb < 16; ++bb) x[bb] = Z[(k1 << 8) + (c << 4) + (bb ^ c)];
    fft16<1>(x);
#pragma unroll
    for (int d = 0; d < 16; ++d) rr[d] = x[d].x;   // Rxx[k1 + 16c + 256d]
  }
  __syncthreads();                                 // all Z reads done; Z free

  // ======== stage V0 + V1 shifted copy ========
  float* Vf = (float*)Z;                           // floats [0..8191]
#pragma unroll
  for (int mm = 0; mm < 4; ++mm) {
    int n0 = (tid << 2) + (mm << 10);
    float4 v = v4s[mm];
    *(float4*)&Vf[n0] = v;                         // V0
    Vf[4096 + ((n0 - 1) & 4095)] = v.x;            // V1: V1[n] = V[(n+1)%N]
    Vf[4096 + n0]     = v.y;
    Vf[4096 + n0 + 1] = v.z;
    Vf[4096 + n0 + 2] = v.w;
  }

  // ======== per-thread sorted top-5 candidates (registers) ========
  const int tbase = (tid >> 4) + ((tid & 15) << 4);
  float c0v=-3e38f,c1v=-3e38f,c2v=-3e38f,c3v=-3e38f,c4v=-3e38f;
  int   c0i=0x7fffffff,c1i=0x7fffffff,c2i=0x7fffffff,c3i=0x7fffffff,c4i=0x7fffffff;
#pragma unroll
  for (int d = 0; d < 16; ++d) {
    float v = rr[d];
    int  gi = tbase + (d << 8);
    bool g0 = v > c0v, g1 = v > c1v, g2 = v > c2v, g3 = v > c3v, g4 = v > c4v;
    c4v = g3 ? c3v : (g4 ? v : c4v);  c4i = g3 ? c3i : (g4 ? gi : c4i);
    c3v = g2 ? c2v : (g3 ? v : c3v);  c3i = g2 ? c2i : (g3 ? gi : c3i);
    c2v = g1 ? c1v : (g2 ? v : c2v);  c2i = g1 ? c1i : (g2 ? gi : c2i);
    c1v = g0 ? c0v : (g1 ? v : c1v);  c1i = g0 ? c0i : (g1 ? gi : c1i);
    c0v = g0 ? v : c0v;               c0i = g0 ? gi : c0i;
  }

  // ======== per-wave top-24 via register merge (parallel on all 4 waves) ====
  {
    int p = 0;
    float myv = 0.f; int myi = 0;
#pragma unroll 1
    for (int t = 0; t < TOPK; ++t) {
      float hv = (p==0)?c0v:(p==1)?c1v:(p==2)?c2v:(p==3)?c3v:(p==4)?c4v:-3e38f;
      int   hi = (p==0)?c0i:(p==1)?c1i:(p==2)?c2i:(p==3)?c3i:(p==4)?c4i:0x7fffffff;
      float bv = hv; int bi = hi;
#pragma unroll
      for (int off = 32; off; off >>= 1) {
        float ov = __shfl_xor(bv, off);
        int   oi = __shfl_xor(bi, off);
        if (ov > bv || (ov == bv && oi < bi)) { bv = ov; bi = oi; }
      }
      p += (hi == bi) ? 1 : 0;       // unique indices: only the winner advances
      if (l == t) { myv = bv; myi = bi; }
    }
    if (l < TOPK) lists[w][l] = make_float2(myv, __int_as_float(myi));
  }
  __syncthreads();   // B1: lists + V0 + V1 visible

  // ======== rank-merge: 96 threads place elements by global rank ========
  if (tid < 4 * TOPK) {
    int w2 = tid / TOPK;
    int i2 = tid - w2 * TOPK;
    float2 me = lists[w2][i2];
    float mv = me.x; int mi = __float_as_int(me.y);
    int rank = i2;
#pragma unroll
    for (int dw = 1; dw < 4; ++dw) {
      int ow = w2 ^ dw;
      int pos = 0;
#pragma unroll
      for (int s = 16; s; s >>= 1) {
        int np = pos + s;
        if (np <= TOPK) {
          float2 o = lists[ow][np - 1];
          float ov = o.x; int oi = __float_as_int(o.y);
          if (ov > mv || (ov == mv && oi < mi)) pos = np;
        }
      }
      rank += pos;
    }
    if (rank < TOPK) pack[rank] = me;
  }
  __syncthreads();   // B2: pack (raw values) visible

  // ======== softmax weights: wave 0, lanes 0..23 ========
  if (tid < 64) {
    float pv0 = pack[0].x;                     // broadcast read (global max)
    float ee = 0.f; int ii = 0;
    if (l < TOPK) {
      float2 p_ = pack[l];
      ee = __expf(p_.x - pv0);
      ii = __float_as_int(p_.y);
    }
    float es = ee;
#pragma unroll
    for (int off = 32; off; off >>= 1) es += __shfl_xor(es, off);
    if (l < TOPK) pack[l] = make_float2(ee, __int_as_float(ii));
    if (l == 0)   pack[TOPK] = make_float2(es, 0.f);
  }
  __syncthreads();   // B3: weights + esum ready

  // ======== gather: A[l] = inv * sum_t e_t * V[(l + i_t) % N] ========
  const float inv = 1.0f / pack[TOPK].x;       // broadcast read
  float2 a0 = make_float2(0,0), a1 = a0, a2 = a0, a3 = a0,
         a4 = a0, a5 = a0, a6 = a0, a7 = a0;
  const int lbase = tid << 1;
#pragma unroll 1
  for (int t = 0; t < TOPK; ++t) {
    float2 p_ = pack[t];                       // broadcast b64
    float e  = p_.x;
    int   ik = __float_as_int(p_.y);
    int base = ik & ~1;
    int pg   = (ik & 1) << 12;
#define GSTEP(acc, MM) { int e0 = (lbase + (MM << 9) + base) & 4095;          \
    float2 vv = *(float2*)&Vf[pg + e0];                                       \
    acc.x += e * vv.x; acc.y += e * vv.y; }
    GSTEP(a0, 0) GSTEP(a1, 1) GSTEP(a2, 2) GSTEP(a3, 3)
    GSTEP(a4, 4) GSTEP(a5, 5) GSTEP(a6, 6) GSTEP(a7, 7)
#undef GSTEP
  }
#define WSTEP(acc, MM) { *(float2*)&At[row + lbase + (MM << 9)] =             \
    make_float2(acc.x * inv, acc.y * inv); }
  WSTEP(a0, 0) WSTEP(a1, 1) WSTEP(a2, 2) WSTEP(a3, 3)
  WSTEP(a4, 4) WSTEP(a5, 5) WSTEP(a6, 6) WSTEP(a7, 7)
#undef WSTEP
}

extern "C" void kernel_launch(void* const* d_in, const int* in_sizes, int n_in,
                              void* d_out, int out_size, void* d_ws, size_t ws_size,
                              hipStream_t stream) {
  const float* Q = (const float*)d_in[0];
  const float* K = (const float*)d_in[1];
  const float* V = (const float*)d_in[2];
  float* out = (float*)d_out;
  float* wsf = (float*)d_ws;

  const int B = 16;
  const size_t SLAB = (size_t)4194304;       // B*L*D floats
  float2* ZQK = (float2*)wsf;                // 2*SLAB floats
  float*  Vt  = wsf + 2 * SLAB;
  float*  At  = Vt;   // alias: block i reads Vt row i (to regs) before writing

  dim3 blk(256);
  transposeQKV<<<dim3(64, B), blk, 0, stream>>>(Q, K, V, ZQK, Vt);
  corr_kernel<<<dim3(B * 64), blk, 0, stream>>>(ZQK, Vt, At);
  transpose64<<<dim3(64, B), blk, 0, stream>>>(At, out, 64, 4096);
}

// Round 9
// 55.108 us; speedup vs baseline: 1.4008x; 1.3399x over previous
//
#include <hip/hip_runtime.h>

// AutoCorrelation attention — register-resident 3-level radix-16 FFT (R5 core)
// + shuffle-free top-k: ballot-based threshold select + single bitonic sort.
// B=16, L=4096, D=64, k=24.

#define FFT_N 4096
#define TOPK  24
#define PI2   6.28318530717958647692f
#define C16_1 0.92387953251128675613f   // cos(pi/8)
#define S16_1 0.38268343236508977173f   // sin(pi/8)
#define C16_2 0.70710678118654752440f   // cos(pi/4)

// LDS layout (bytes). V images have 512-float wraparound pads.
#define V1OFF   4608                    // float index of V1 image
#define SM_CAND 36864                   // float2[64]
#define SM_C0   37376                   // float[256]
#define SM_PACK 38400                   // float2[25]
#define SM_CNT  38608                   // int
#define SM_THR  38612                   // float
#define SM_SIZE 38624

__device__ __forceinline__ float2 cmul(float2 a, float2 b) {
  return make_float2(a.x*b.x - a.y*b.y, a.x*b.y + a.y*b.x);
}

// monotone float->uint key (order-preserving incl. negatives)
__device__ __forceinline__ unsigned fkey(float f) {
  int b = __float_as_int(f);
  return (unsigned)(b ^ ((b >> 31) | 0x80000000));
}

// 16-point DFT, natural order in and out. S=-1 forward, S=+1 inverse.
template<int S>
__device__ __forceinline__ void fft16(float2* x) {
  const float sg = (float)S;
  float2 y[16];
#pragma unroll
  for (int n2 = 0; n2 < 4; ++n2) {
    float2 a = x[n2], b = x[4+n2], c = x[8+n2], d = x[12+n2];
    float t0r=a.x+c.x, t0i=a.y+c.y, t1r=a.x-c.x, t1i=a.y-c.y;
    float t2r=b.x+d.x, t2i=b.y+d.y, t3r=b.x-d.x, t3i=b.y-d.y;
    y[n2*4+0] = make_float2(t0r+t2r, t0i+t2i);
    y[n2*4+2] = make_float2(t0r-t2r, t0i-t2i);
    y[n2*4+1] = make_float2(t1r - sg*t3i, t1i + sg*t3r);
    y[n2*4+3] = make_float2(t1r + sg*t3i, t1i - sg*t3r);
  }
#define CTW(ii, cc, ss) { float2 v=y[ii]; y[ii]=make_float2(v.x*(cc)-v.y*(sg*(ss)), v.x*(sg*(ss))+v.y*(cc)); }
  CTW(5,  C16_1, S16_1)
  CTW(6,  C16_2, C16_2)
  CTW(7,  S16_1, C16_1)
  CTW(9,  C16_2, C16_2)
  { float2 v = y[10]; y[10] = make_float2(-sg*v.y, sg*v.x); }
  CTW(11, -C16_2, C16_2)
  CTW(13, S16_1, C16_1)
  CTW(14, -C16_2, C16_2)
  CTW(15, -C16_1, -S16_1)
#undef CTW
#pragma unroll
  for (int k1 = 0; k1 < 4; ++k1) {
    float2 a = y[k1], b = y[4+k1], c = y[8+k1], d = y[12+k1];
    float t0r=a.x+c.x, t0i=a.y+c.y, t1r=a.x-c.x, t1i=a.y-c.y;
    float t2r=b.x+d.x, t2i=b.y+d.y, t3r=b.x-d.x, t3i=b.y-d.y;
    x[k1+0]  = make_float2(t0r+t2r, t0i+t2i);
    x[k1+8]  = make_float2(t0r-t2r, t0i-t2i);
    x[k1+4]  = make_float2(t1r - sg*t3i, t1i + sg*t3r);
    x[k1+12] = make_float2(t1r + sg*t3i, t1i - sg*t3r);
  }
}

// x[k] *= w^k, k=1..15; powers via depth-4 product tree.
__device__ __forceinline__ void twiddle_chain(float2* x, float ang) {
  float sb, cb; __sincosf(ang, &sb, &cb);
  float2 w1 = make_float2(cb, sb);
  float2 w2 = cmul(w1,w1), w3 = cmul(w1,w2);
  float2 w4 = cmul(w2,w2), w5 = cmul(w2,w3), w6 = cmul(w3,w3), w7 = cmul(w3,w4);
  float2 w8 = cmul(w4,w4), w9 = cmul(w4,w5), w10 = cmul(w5,w5), w11 = cmul(w5,w6);
  float2 w12 = cmul(w6,w6), w13 = cmul(w6,w7), w14 = cmul(w7,w7), w15 = cmul(w7,w8);
  x[1]=cmul(x[1],w1);   x[2]=cmul(x[2],w2);   x[3]=cmul(x[3],w3);
  x[4]=cmul(x[4],w4);   x[5]=cmul(x[5],w5);   x[6]=cmul(x[6],w6);
  x[7]=cmul(x[7],w7);   x[8]=cmul(x[8],w8);   x[9]=cmul(x[9],w9);
  x[10]=cmul(x[10],w10); x[11]=cmul(x[11],w11); x[12]=cmul(x[12],w12);
  x[13]=cmul(x[13],w13); x[14]=cmul(x[14],w14); x[15]=cmul(x[15],w15);
}

// Q,K,V [B,L,D] -> ZQK interleaved float2 [B,D,L] + Vt [B,D,L]
__global__ __launch_bounds__(256) void transposeQKV(const float* __restrict__ Q,
                                                    const float* __restrict__ K,
                                                    const float* __restrict__ V,
                                                    float2* __restrict__ ZQK,
                                                    float* __restrict__ Vt) {
  __shared__ float tq[64][65];
  __shared__ float tk[64][65];
  __shared__ float tv[64][65];
  const int b = blockIdx.y;
  const int t0 = blockIdx.x << 6;
  const float* Qb = Q + ((size_t)b << 18);
  const float* Kb = K + ((size_t)b << 18);
  const float* Vb = V + ((size_t)b << 18);
  int tx = threadIdx.x & 63, ty = threadIdx.x >> 6;
#pragma unroll
  for (int i = 0; i < 16; ++i) {
    int r = (i << 2) + ty;
    tq[r][tx] = Qb[(size_t)(t0 + r) * 64 + tx];
    tk[r][tx] = Kb[(size_t)(t0 + r) * 64 + tx];
    tv[r][tx] = Vb[(size_t)(t0 + r) * 64 + tx];
  }
  __syncthreads();
  float2* zoutb = ZQK + ((size_t)b << 18);
  float*  voutb = Vt + ((size_t)b << 18);
#pragma unroll
  for (int i = 0; i < 16; ++i) {
    int d = (i << 2) + ty;
    zoutb[(size_t)d * 4096 + t0 + tx] = make_float2(tq[tx][d], tk[tx][d]);
    voutb[(size_t)d * 4096 + t0 + tx] = tv[tx][d];
  }
}

__global__ __launch_bounds__(256) void transpose64(const float* __restrict__ in,
                                                   float* __restrict__ out,
                                                   int R, int C) {
  __shared__ float tile[64][65];
  int tiles_c = C >> 6;
  int tr = blockIdx.x / tiles_c;
  int tc = blockIdx.x - tr * tiles_c;
  const float* inb = in + (size_t)blockIdx.y * R * C;
  float* outb = out + (size_t)blockIdx.y * R * C;
  int tx = threadIdx.x & 63;
  int ty = threadIdx.x >> 6;
  int r0 = tr << 6, c0 = tc << 6;
#pragma unroll
  for (int i = 0; i < 16; ++i) {
    int r = (i << 2) + ty;
    tile[r][tx] = inb[(size_t)(r0 + r) * C + (c0 + tx)];
  }
  __syncthreads();
#pragma unroll
  for (int i = 0; i < 16; ++i) {
    int r = (i << 2) + ty;
    outb[(size_t)(c0 + r) * R + (r0 + tx)] = tile[tx][r];
  }
}

__global__ __launch_bounds__(256, 4) void corr_kernel(const float2* __restrict__ ZQK,
                                                      const float* __restrict__ Vt,
                                                      float* __restrict__ At) {
  __shared__ __align__(16) unsigned char smem[SM_SIZE];
  float2* Z = (float2*)smem;           // FFT workspace (32 KiB), later V images

  const int tid = threadIdx.x;
  const size_t row = (size_t)blockIdx.x << 12;

  float2 x[16];

  // ======== forward FFT of z = q + i*k (R5 core) ========
#pragma unroll
  for (int n1 = 0; n1 < 16; ++n1)
    x[n1] = ZQK[row + (n1 << 8) + tid];
  fft16<-1>(x);
  twiddle_chain(x, -PI2 * (float)tid / 4096.f);
#pragma unroll
  for (int k = 0; k < 16; ++k) Z[(k << 8) + tid] = x[k];
  __syncthreads();
  {
    const int k1 = tid >> 4, b = tid & 15;
#pragma unroll
    for (int a = 0; a < 16; ++a) x[a] = Z[(k1 << 8) + (a << 4) + b];
    fft16<-1>(x);
    twiddle_chain(x, -PI2 * (float)b / 256.f);
    __syncthreads();
#pragma unroll
    for (int cc = 0; cc < 16; ++cc) Z[(k1 << 8) + (cc << 4) + (b ^ cc)] = x[cc];
  }
  __syncthreads();
  {
    const int k1 = tid >> 4, c = tid & 15;
#pragma unroll
    for (int bb = 0; bb < 16; ++bb) x[bb] = Z[(k1 << 8) + (c << 4) + (bb ^ c)];
    fft16<-1>(x);
    __syncthreads();
    const int bf = k1 + (c << 4);
#pragma unroll
    for (int d = 0; d < 16; ++d) Z[(bf ^ c) + (d << 8)] = x[d];
  }
  __syncthreads();

  // ======== pointwise P = Qf*conj(Kf) * (1/4N) ========
  {
    const float scale = 0.25f / 4096.f;
    const int x1 = tid >> 4;
#pragma unroll
    for (int f1 = 0; f1 < 16; ++f1) {
      int f  = (f1 << 8) + tid;
      int fp = (4096 - f) & 4095;
      float2 A  = Z[f ^ x1];
      float2 Bv = Z[fp ^ ((fp >> 4) & 15)];
      float ur = A.x + Bv.x, ui = A.y - Bv.y;
      float vr = A.x - Bv.x, vi = -A.y - Bv.y;
      float xr = ur*vr - ui*vi, xi = ur*vi + ui*vr;
      x[f1] = make_float2(-xi * scale, xr * scale);
    }
  }

  // prefetch V row (latency hidden under inverse FFT)
  float4 v4s[4];
#pragma unroll
  for (int mm = 0; mm < 4; ++mm)
    v4s[mm] = *(const float4*)&Vt[row + (tid << 2) + (mm << 10)];

  // ======== inverse FFT (R5 core) ========
  fft16<1>(x);
  twiddle_chain(x, PI2 * (float)tid / 4096.f);
  __syncthreads();
#pragma unroll
  for (int k = 0; k < 16; ++k) Z[(k << 8) + tid] = x[k];
  __syncthreads();
  {
    const int k1 = tid >> 4, b = tid & 15;
#pragma unroll
    for (int a = 0; a < 16; ++a) x[a] = Z[(k1 << 8) + (a << 4) + b];
    fft16<1>(x);
    twiddle_chain(x, PI2 * (float)b / 256.f);
    __syncthreads();
#pragma unroll
    for (int cc = 0; cc < 16; ++cc) Z[(k1 << 8) + (cc << 4) + (b ^ cc)] = x[cc];
  }
  __syncthreads();
  float rr[16];
  {
    const int k1 = tid >> 4, c = tid & 15;
#pragma unroll
    for (int bb = 0; bb < 16; ++bb) x[bb] = Z[(k1 << 8) + (c << 4) + (bb ^ c)];
    fft16<1>(x);
#pragma unroll
    for (int d = 0; d < 16; ++d) rr[d] = x[d].x;   // Rxx[k1 + 16c + 256d]
  }
  __syncthreads();                                 // all Z reads done; Z free

  // ======== stage V0ext + V1ext (512-float wrap pads) + c0 ========
  float* Vf = (float*)smem;
#pragma unroll
  for (int mm = 0; mm < 4; ++mm) {
    int n0 = (tid << 2) + (mm << 10);
    float4 v = v4s[mm];
    *(float4*)&Vf[n0] = v;                         // V0 main
    Vf[V1OFF + ((n0 - 1) & 4095)] = v.x;           // V1[n]=V[(n+1)%N]
    Vf[V1OFF + n0]     = v.y;
    Vf[V1OFF + n0 + 1] = v.z;
    Vf[V1OFF + n0 + 2] = v.w;
  }
  {
    float4 v = v4s[0];
    if (tid < 128) {                               // pads: V*ext[4096+j]
      *(float4*)&Vf[4096 + (tid << 2)] = v;        // V0 pad = V[0..511]
      Vf[V1OFF + 4096 + (tid << 2) + 0] = v.y;     // V1 pad[4t]   = V[4t+1]
      Vf[V1OFF + 4096 + (tid << 2) + 1] = v.z;
      Vf[V1OFF + 4096 + (tid << 2) + 2] = v.w;
    }
    if (tid >= 1 && tid <= 128)
      Vf[V1OFF + 4096 + (tid << 2) - 1] = v.x;     // V1 pad[4t-1] = V[4t]
  }
  float c0v = rr[0];
#pragma unroll
  for (int d = 1; d < 16; ++d) c0v = fmaxf(c0v, rr[d]);
  ((float*)(smem + SM_C0))[tid] = c0v;
  if (tid == 0) *(int*)(smem + SM_CNT) = 0;
  __syncthreads();   // B1

  // ======== wave0: ballot binsearch for threshold (top-16 key bits) ========
  if (tid < 64) {
    const float* c0b = (const float*)(smem + SM_C0);
    unsigned k0 = fkey(c0b[tid]);
    unsigned k1 = fkey(c0b[tid + 64]);
    unsigned k2 = fkey(c0b[tid + 128]);
    unsigned k3 = fkey(c0b[tid + 192]);
    unsigned T = 0;
    for (int b = 31; b >= 16; --b) {
      unsigned T2 = T | (1u << b);
      int c = (k0 >= T2) + (k1 >= T2) + (k2 >= T2) + (k3 >= T2);
      unsigned long long b0 = __ballot(c & 1);
      unsigned long long b1 = __ballot(c & 2);
      unsigned long long b2 = __ballot(c & 4);
      int cnt = __popcll(b0) + 2 * __popcll(b1) + 4 * __popcll(b2);
      if (cnt >= TOPK) T = T2;
    }
    if (tid == 0) {
      float thrF;
      if (T == 0) thrF = -3e38f;
      else {
        int ib = (T & 0x80000000u) ? (int)(T ^ 0x80000000u) : (int)~T;
        thrF = __int_as_float(ib);
      }
      *(float*)(smem + SM_THR) = thrF;
    }
  }
  __syncthreads();   // B2

  // ======== extraction: append (val, idx) with rr >= thr ========
  {
    const float thrF = *(const float*)(smem + SM_THR);
    int* cnt = (int*)(smem + SM_CNT);
    float2* cand = (float2*)(smem + SM_CAND);
    const int tb = (tid >> 4) + ((tid & 15) << 4);
#pragma unroll
    for (int d = 0; d < 16; ++d) {
      if (rr[d] >= thrF) {
        int pos = atomicAdd(cnt, 1);
        if (pos < 64)
          cand[pos] = make_float2(rr[d], __int_as_float(tb + (d << 8)));
      }
    }
  }
  __syncthreads();   // B3

  // ======== wave0: bitonic sort 64 desc (val, idx asc), softmax, pack ========
  if (tid < 64) {
    const float2* cand = (const float2*)(smem + SM_CAND);
    int NC = *(const int*)(smem + SM_CNT);
    NC = NC < 64 ? NC : 64;
    float v; int ix;
    if (tid < NC) { float2 cc = cand[tid]; v = cc.x; ix = __float_as_int(cc.y); }
    else          { v = -3e38f; ix = 0x7fffffff; }
#pragma unroll
    for (int k = 2; k <= 64; k <<= 1) {
#pragma unroll
      for (int j = k >> 1; j > 0; j >>= 1) {
        float ov = __shfl_xor(v, j);
        int   oi = __shfl_xor(ix, j);
        bool iless  = (tid & j) == 0;
        bool dird   = (tid & k) == 0;
        bool better = (v > ov) || (v == ov && ix < oi);
        bool keep   = ((iless == dird) == better);
        v  = keep ? v  : ov;
        ix = keep ? ix : oi;
      }
    }
    float m0 = __shfl(v, 0);
    float e = (tid < TOPK) ? __expf(v - m0) : 0.f;
    float es = e;
#pragma unroll
    for (int off = 32; off; off >>= 1) es += __shfl_xor(es, off);
    float2* pack = (float2*)(smem + SM_PACK);
    if (tid < TOPK) pack[tid] = make_float2(e, __int_as_float(ix));
    if (tid == 0)   pack[TOPK] = make_float2(es, 0.f);
  }
  __syncthreads();   // B4

  // ======== gather: A[l] = inv * sum_t e_t * V[(l + i_t) % N] ========
  const float2* pack = (const float2*)(smem + SM_PACK);
  const float inv = 1.0f / pack[TOPK].x;
  float2 a0 = make_float2(0,0), a1=a0, a2=a0, a3=a0, a4=a0, a5=a0, a6=a0, a7=a0;
  const int lbase = tid << 1;
#pragma unroll 1
  for (int t = 0; t < TOPK; ++t) {
    float2 p_ = pack[t];
    float e  = p_.x;
    int   ik = __float_as_int(p_.y);
    int base = ik & ~1;
    const float* Vb = Vf + ((ik & 1) ? V1OFF : 0);
    int e0 = (lbase        + base) & 4095;
    int e1 = (lbase + 1024 + base) & 4095;
    int e2 = (lbase + 2048 + base) & 4095;
    int e3 = (lbase + 3072 + base) & 4095;
    float2 v00 = *(const float2*)&Vb[e0];
    float2 v01 = *(const float2*)&Vb[e0 + 512];    // pad makes this valid
    float2 v10 = *(const float2*)&Vb[e1];
    float2 v11 = *(const float2*)&Vb[e1 + 512];
    float2 v20 = *(const float2*)&Vb[e2];
    float2 v21 = *(const float2*)&Vb[e2 + 512];
    float2 v30 = *(const float2*)&Vb[e3];
    float2 v31 = *(const float2*)&Vb[e3 + 512];
    a0.x += e*v00.x; a0.y += e*v00.y;
    a1.x += e*v01.x; a1.y += e*v01.y;
    a2.x += e*v10.x; a2.y += e*v10.y;
    a3.x += e*v11.x; a3.y += e*v11.y;
    a4.x += e*v20.x; a4.y += e*v20.y;
    a5.x += e*v21.x; a5.y += e*v21.y;
    a6.x += e*v30.x; a6.y += e*v30.y;
    a7.x += e*v31.x; a7.y += e*v31.y;
  }
  *(float2*)&At[row + lbase]        = make_float2(a0.x*inv, a0.y*inv);
  *(float2*)&At[row + lbase + 512]  = make_float2(a1.x*inv, a1.y*inv);
  *(float2*)&At[row + lbase + 1024] = make_float2(a2.x*inv, a2.y*inv);
  *(float2*)&At[row + lbase + 1536] = make_float2(a3.x*inv, a3.y*inv);
  *(float2*)&At[row + lbase + 2048] = make_float2(a4.x*inv, a4.y*inv);
  *(float2*)&At[row + lbase + 2560] = make_float2(a5.x*inv, a5.y*inv);
  *(float2*)&At[row + lbase + 3072] = make_float2(a6.x*inv, a6.y*inv);
  *(float2*)&At[row + lbase + 3584] = make_float2(a7.x*inv, a7.y*inv);
}

extern "C" void kernel_launch(void* const* d_in, const int* in_sizes, int n_in,
                              void* d_out, int out_size, void* d_ws, size_t ws_size,
                              hipStream_t stream) {
  const float* Q = (const float*)d_in[0];
  const float* K = (const float*)d_in[1];
  const float* V = (const float*)d_in[2];
  float* out = (float*)d_out;
  float* wsf = (float*)d_ws;

  const int B = 16;
  const size_t SLAB = (size_t)4194304;       // B*L*D floats
  float2* ZQK = (float2*)wsf;                // 2*SLAB floats
  float*  Vt  = wsf + 2 * SLAB;
  float*  At  = Vt;   // alias: block i reads Vt row i (to regs) before writing

  dim3 blk(256);
  transposeQKV<<<dim3(64, B), blk, 0, stream>>>(Q, K, V, ZQK, Vt);
  corr_kernel<<<dim3(B * 64), blk, 0, stream>>>(ZQK, Vt, At);
  transpose64<<<dim3(64, B), blk, 0, stream>>>(At, out, 64, 4096);
}